// Round 2
// baseline (259.822 us; speedup 1.0000x reference)
//
#include <hip/hip_runtime.h>

// NCC weight loss, fused single-kernel. v3 (= v2 de-risked):
//  - software-pipelined global loads: next z-plane (I,J) and next Wm tile are
//    issued one iteration ahead into registers; fused "s_waitcnt lgkmcnt(0);
//    s_barrier" (no vmcnt drain) keeps them in flight across both barriers.
//  - sx row stride padded 32 -> 36 floats: kills Phase C's 8-way bank conflict.
//  - Phase C widened to 128 threads x 2 outputs (float2).
//  - plain z-loop (no forced unroll, no lambda) to minimize compile risk.
// Dims fixed: (N=2, C=1, D=160, H=192, W=224), win=5, fp32.
#define N_  2
#define D_  160
#define H_  192
#define W_  224
#define TW  32            // output tile width (x)
#define TH  8             // output tile height (y)
#define ZCH 32            // z-chunk per block
#define NZC (D_/ZCH)      // 5
#define HWH (TW+4)        // 36 halo width
#define HHH (TH+4)        // 12 halo height
#define SXW (TW+4)        // 36: padded sx row stride (144B, 16B-aligned)
#define PL  (H_*W_)       // 43008 plane stride
#define TOT (N_*D_*H_*W_) // 13,762,560

#define BAR() asm volatile("s_waitcnt lgkmcnt(0)\n\ts_barrier" ::: "memory")

__global__ __launch_bounds__(256) void ncc_kernel(
    const float* __restrict__ I, const float* __restrict__ J,
    const float* __restrict__ Wm, float* __restrict__ out)
{
    __shared__ __align__(16) float zsL[5][HHH][HWH]; // z-summed quantities
    __shared__ __align__(16) float sx [5][HHH][SXW]; // x-box-summed (padded)
    __shared__ float red[4];

    const int tid = threadIdx.x;
    const int bx = blockIdx.x, by = blockIdx.y;
    const int n  = blockIdx.z / NZC;
    const int c0 = (blockIdx.z % NZC) * ZCH;
    const int wbase = bx * TW - 2;
    const int hbase = by * TH - 2;

    // ---- Phase A ownership: 216 threads own 2 adjacent halo columns each ----
    const bool aAct = tid < 216;
    const int arow = tid / 18;          // 0..11
    const int ag   = tid % 18;          // 0..17 (column pair)
    const int ah   = hbase + arow;
    const int aw0  = wbase + 2 * ag;    // even -> float2-aligned; aw0 ok => aw0+1 ok
    const bool aok = aAct && ((unsigned)ah < (unsigned)H_)
                          && ((unsigned)aw0 < (unsigned)W_);
    const int abase = (n * D_) * PL + ah * W_ + aw0;  // + z*PL

    // ---- Phase B ownership: 96 threads, 4 x-outputs each ----
    const bool bAct = tid < 96;
    const int brow = tid >> 3;          // 0..11
    const int bxo  = (tid & 7) * 4;     // 0,4,...,28

    // ---- Phase C ownership: 128 threads, 2 outputs each ----
    const bool cAct = tid < 128;
    const int cty = tid >> 4;           // 0..7
    const int cx0 = (tid & 15) * 2;     // 0,2,...,30
    const int ch  = by * TH + cty;
    const int cw  = bx * TW + cx0;      // even -> float2-aligned
    const int wmbase = (n * D_) * PL + ch * W_ + cw;  // + zo*PL

    // per-column z-ring of raw I,J (5 deep) + incremental z-sums (5 quantities)
    float rI0[5], rJ0[5], rI1[5], rJ1[5], zs0[5], zs1[5];
#pragma unroll
    for (int k = 0; k < 5; ++k) {
        rI0[k]=0.f; rJ0[k]=0.f; rI1[k]=0.f; rJ1[k]=0.f; zs0[k]=0.f; zs1[k]=0.f;
    }

    float acc = 0.f;
    const float inv125 = 1.0f / 125.0f;

    // current-plane raw values (integrated by this iteration) — prologue load
    float cI0=0.f, cI1=0.f, cJ0=0.f, cJ1=0.f;
    {
        const int z = c0 - 2;
        if (aok && (unsigned)z < (unsigned)D_) {
            const float2 i2 = *(const float2*)&I[abase + z * PL];
            const float2 j2 = *(const float2*)&J[abase + z * PL];
            cI0=i2.x; cI1=i2.y; cJ0=j2.x; cJ1=j2.y;
        }
    }
    float wmCx = 0.f, wmCy = 0.f;  // Wm tile for this iteration's Phase C

    for (int s = 0; s < ZCH + 4; ++s) {
        const int z = c0 - 2 + s;
        const int zo = z - 2;

        // ---- prefetch next z-plane (I,J) into registers (used next iteration)
        float nI0=0.f, nI1=0.f, nJ0=0.f, nJ1=0.f;
        {
            const int zn = z + 1;
            if (aok && (unsigned)zn < (unsigned)D_ && s < ZCH + 3) {
                const float2 i2 = *(const float2*)&I[abase + zn * PL];
                const float2 j2 = *(const float2*)&J[abase + zn * PL];
                nI0=i2.x; nI1=i2.y; nJ0=j2.x; nJ1=j2.y;
            }
        }
        // ---- prefetch next iteration's Wm tile
        float wmNx = 0.f, wmNy = 0.f;
        {
            const int zon = zo + 1;
            if (cAct && zon >= c0 && zon < c0 + ZCH) {
                const float2 w2 = *(const float2*)&Wm[wmbase + zon * PL];
                wmNx = w2.x; wmNy = w2.y;
            }
        }

        // ---- Phase A: integrate current plane into z-ring, stage z-sums to LDS
        if (aAct) {
            {   // column 0
                const float oi = rI0[0], oj = rJ0[0];
                zs0[0] += cI0 - oi;
                zs0[1] += cJ0 - oj;
                zs0[2] += cI0*cI0 - oi*oi;
                zs0[3] += cJ0*cJ0 - oj*oj;
                zs0[4] += cI0*cJ0 - oi*oj;
#pragma unroll
                for (int k = 0; k < 4; ++k) { rI0[k]=rI0[k+1]; rJ0[k]=rJ0[k+1]; }
                rI0[4]=cI0; rJ0[4]=cJ0;
            }
            {   // column 1
                const float oi = rI1[0], oj = rJ1[0];
                zs1[0] += cI1 - oi;
                zs1[1] += cJ1 - oj;
                zs1[2] += cI1*cI1 - oi*oi;
                zs1[3] += cJ1*cJ1 - oj*oj;
                zs1[4] += cI1*cJ1 - oi*oj;
#pragma unroll
                for (int k = 0; k < 4; ++k) { rI1[k]=rI1[k+1]; rJ1[k]=rJ1[k+1]; }
                rI1[4]=cI1; rJ1[4]=cJ1;
            }
#pragma unroll
            for (int a = 0; a < 5; ++a)
                *(float2*)&zsL[a][arow][2*ag] = make_float2(zs0[a], zs1[a]);
        }
        // raw barrier: drain LDS only — prefetched global loads stay in flight
        BAR();

        // ---- Phase B: x box-sum (36 -> 32), 4 outputs per thread
        if (bAct) {
#pragma unroll
            for (int a = 0; a < 5; ++a) {
                const float4 v0 = *(const float4*)&zsL[a][brow][bxo];
                const float4 v1 = *(const float4*)&zsL[a][brow][bxo + 4];
                const float m  = v0.y + v0.z + v0.w;       // middle prefix
                const float u1 = v1.x + v1.y;
                const float u2 = u1 + v1.z;
                *(float4*)&sx[a][brow][bxo] =
                    make_float4(v0.x + m + v1.x, m + u1,
                                (v0.z + v0.w) + u2, v0.w + (u2 + v1.w));
            }
        }
        BAR();

        // ---- Phase C: y box-sum + cc + weighted accumulate, 2 outputs/thread
        if (cAct && zo >= c0) {
            float2 S[5];
#pragma unroll
            for (int a = 0; a < 5; ++a) {
                float2 v = *(const float2*)&sx[a][cty][cx0];
#pragma unroll
                for (int k = 1; k < 5; ++k) {
                    const float2 w = *(const float2*)&sx[a][cty + k][cx0];
                    v.x += w.x; v.y += w.y;
                }
                S[a] = v;
            }
            {
                const float cr = S[4].x - S[0].x * S[1].x * inv125;
                const float vi = S[2].x - S[0].x * S[0].x * inv125;
                const float vj = S[3].x - S[1].x * S[1].x * inv125;
                acc += wmCx * (cr * cr) * __builtin_amdgcn_rcpf(vi * vj + 1e-8f);
            }
            {
                const float cr = S[4].y - S[0].y * S[1].y * inv125;
                const float vi = S[2].y - S[0].y * S[0].y * inv125;
                const float vj = S[3].y - S[1].y * S[1].y * inv125;
                acc += wmCy * (cr * cr) * __builtin_amdgcn_rcpf(vi * vj + 1e-8f);
            }
        }
        // rotate pipeline registers
        cI0=nI0; cI1=nI1; cJ0=nJ0; cJ1=nJ1;
        wmCx = wmNx; wmCy = wmNy;
        // next Phase A writes zsL: safe — every wave drained its B-reads of zsL
        // before the second barrier, and Phase C only touches sx.
    }

    // Block reduction: wave64 shuffle, then cross-wave via LDS
#pragma unroll
    for (int off = 32; off > 0; off >>= 1)
        acc += __shfl_down(acc, off, 64);
    const int wave = tid >> 6;
    const int lane = tid & 63;
    if (lane == 0) red[wave] = acc;
    __syncthreads();
    if (tid == 0) {
        const float t = red[0] + red[1] + red[2] + red[3];
        atomicAdd(out, t * (-1.0f / (float)TOT));
    }
}

extern "C" void kernel_launch(void* const* d_in, const int* in_sizes, int n_in,
                              void* d_out, int out_size, void* d_ws, size_t ws_size,
                              hipStream_t stream)
{
    const float* I  = (const float*)d_in[0];
    const float* J  = (const float*)d_in[1];
    const float* Wm = (const float*)d_in[2];
    float* out = (float*)d_out;

    hipMemsetAsync(out, 0, sizeof(float), stream);

    dim3 grid(W_ / TW, H_ / TH, N_ * NZC);  // (7, 24, 10) = 1680 blocks
    dim3 block(256);
    hipLaunchKernelGGL(ncc_kernel, grid, block, 0, stream, I, J, Wm, out);
}

// Round 3
// 201.635 us; speedup vs baseline: 1.2886x; 1.2886x over previous
//
#include <hip/hip_runtime.h>

// NCC weight loss, fused single-kernel. v4: amortize the per-iteration barrier
// chain over 2x voxels (TH 8->16, 512 outputs/plane/block), all 4 waves active
// in Phase C, branch-free clamped+masked Phase A loads (counted vmcnt), b128
// LDS staging. Grid 840 blocks, 29KB LDS, VGPR capped 128 -> 4 blocks/CU.
// Dims fixed: (N=2, C=1, D=160, H=192, W=224), win=5, fp32.
#define N_  2
#define D_  160
#define H_  192
#define W_  224
#define TW  32            // output tile width  (x)
#define TH  16            // output tile height (y)
#define ZCH 32            // z-chunk per block
#define NZC (D_/ZCH)      // 5
#define HR  (TH+4)        // 20 halo rows
#define HC  (TW+4)        // 36 halo cols (also padded stride: 144B, 16B-aligned)
#define PL  (H_*W_)       // 43008 plane stride
#define TOT (N_*D_*H_*W_) // 13,762,560

#define BAR() asm volatile("s_waitcnt lgkmcnt(0)\n\ts_barrier" ::: "memory")

__global__ __launch_bounds__(256, 4) void ncc_kernel(
    const float* __restrict__ I, const float* __restrict__ J,
    const float* __restrict__ Wm, float* __restrict__ out)
{
    __shared__ __align__(16) float zsL[5][HR][HC]; // z-summed quantities
    __shared__ __align__(16) float sx [5][HR][HC]; // x-box-summed
    __shared__ float red[4];

    const int tid = threadIdx.x;
    const int bx = blockIdx.x, by = blockIdx.y;
    const int n  = blockIdx.z / NZC;
    const int c0 = (blockIdx.z % NZC) * ZCH;
    const int nbase = n * D_ * PL;

    // ---- Phase A: 180 threads, 4 halo columns each (two aligned float2 loads)
    const bool aAct = tid < 180;
    const int arow = tid / 9;                 // 0..19
    const int ag   = tid % 9;                 // 0..8
    const int ah   = by * TH - 2 + arow;
    const int ahc  = min(max(ah, 0), H_ - 1);
    const int aw0  = bx * TW - 2 + 4 * ag;    // even
    const bool mH  = (ah == ahc);
    const bool mW0 = (aw0 >= 0);              // pair0 = cols aw0, aw0+1
    const bool mW1 = (aw0 + 3 < W_);          // pair1 = cols aw0+2, aw0+3
    const int awc0 = max(aw0, 0);
    const int awc1 = min(aw0 + 2, W_ - 4);
    const int preA0 = nbase + ahc * W_ + awc0;   // + z*PL
    const int preA1 = nbase + ahc * W_ + awc1;

    // ---- Phase B: 160 threads, 4 x-outputs each
    const bool bAct = tid < 160;
    const int brow = tid >> 3;                // 0..19
    const int bxo  = (tid & 7) * 4;           // 0..28

    // ---- Phase C: 256 threads, 2 outputs each
    const int cty = tid >> 4;                 // 0..15
    const int cx0 = (tid & 15) * 2;           // 0..30
    const int ch  = by * TH + cty;
    const int cw  = bx * TW + cx0;            // even
    const int preW = nbase + ch * W_ + cw;    // + zo*PL

    // per-column z-ring of raw I,J (5 deep) + incremental z-sums (5 quantities)
    float rI[4][5], rJ[4][5], zs[5][4];
#pragma unroll
    for (int c = 0; c < 4; ++c)
#pragma unroll
        for (int k = 0; k < 5; ++k) { rI[c][k] = 0.f; rJ[c][k] = 0.f; }
#pragma unroll
    for (int a = 0; a < 5; ++a)
#pragma unroll
        for (int c = 0; c < 4; ++c) zs[a][c] = 0.f;

    float acc = 0.f;
    const float inv125 = 1.0f / 125.0f;

    // current-plane raw values (masked), consumed by this iteration's Phase A
    float cI[4] = {0.f,0.f,0.f,0.f}, cJ[4] = {0.f,0.f,0.f,0.f};
    {
        const int z0 = c0 - 2;
        const int zc = min(max(z0, 0), D_ - 1);
        const bool mZ = (z0 == zc);
        const int zoff = zc * PL;
        if (aAct) {
            const float2 i0 = *(const float2*)&I[preA0 + zoff];
            const float2 i1 = *(const float2*)&I[preA1 + zoff];
            const float2 j0 = *(const float2*)&J[preA0 + zoff];
            const float2 j1 = *(const float2*)&J[preA1 + zoff];
            const float f0 = (mH && mW0 && mZ) ? 1.f : 0.f;
            const float f1 = (mH && mW1 && mZ) ? 1.f : 0.f;
            cI[0]=i0.x*f0; cI[1]=i0.y*f0; cI[2]=i1.x*f1; cI[3]=i1.y*f1;
            cJ[0]=j0.x*f0; cJ[1]=j0.y*f0; cJ[2]=j1.x*f1; cJ[3]=j1.y*f1;
        }
    }
    float wmCx = 0.f, wmCy = 0.f;   // Wm tile for this iteration's Phase C

    for (int s = 0; s < ZCH + 4; ++s) {
        // ---- prefetch next z-plane (z+1) into registers — unconditional,
        //      clamped address + mask; stays in flight across both barriers
        const int zn  = c0 - 1 + s;
        const int znc = min(max(zn, 0), D_ - 1);
        const bool mZn = (zn == znc);
        const int zoffn = znc * PL;
        float2 pi0, pi1, pj0, pj1;
        if (aAct) {
            pi0 = *(const float2*)&I[preA0 + zoffn];
            pi1 = *(const float2*)&I[preA1 + zoffn];
            pj0 = *(const float2*)&J[preA0 + zoffn];
            pj1 = *(const float2*)&J[preA1 + zoffn];
        } else {
            pi0 = pi1 = pj0 = pj1 = make_float2(0.f, 0.f);
        }
        // ---- prefetch next iteration's Wm tile (clamped, unconditional)
        const int zon  = c0 - 3 + s;
        const int zonc = min(max(zon, 0), D_ - 1);
        const float2 wmN = *(const float2*)&Wm[preW + zonc * PL];

        // ---- Phase A: integrate current plane into z-ring, stage z-sums (b128)
        if (aAct) {
#pragma unroll
            for (int c = 0; c < 4; ++c) {
                const float vi = cI[c], vj = cJ[c];
                const float oi = rI[c][0], oj = rJ[c][0];
                zs[0][c] += vi - oi;
                zs[1][c] += vj - oj;
                zs[2][c] += vi*vi - oi*oi;
                zs[3][c] += vj*vj - oj*oj;
                zs[4][c] += vi*vj - oi*oj;
#pragma unroll
                for (int k = 0; k < 4; ++k) { rI[c][k]=rI[c][k+1]; rJ[c][k]=rJ[c][k+1]; }
                rI[c][4] = vi; rJ[c][4] = vj;
            }
#pragma unroll
            for (int a = 0; a < 5; ++a)
                *(float4*)&zsL[a][arow][4*ag] =
                    make_float4(zs[a][0], zs[a][1], zs[a][2], zs[a][3]);
        }
        BAR();   // lgkm drain only — prefetched globals stay in flight

        // ---- Phase B: x box-sum (36 -> 32), 4 outputs per thread
        if (bAct) {
#pragma unroll
            for (int a = 0; a < 5; ++a) {
                const float4 v0 = *(const float4*)&zsL[a][brow][bxo];
                const float4 v1 = *(const float4*)&zsL[a][brow][bxo + 4];
                const float m  = v0.y + v0.z + v0.w;
                const float u1 = v1.x + v1.y;
                const float u2 = u1 + v1.z;
                *(float4*)&sx[a][brow][bxo] =
                    make_float4(v0.x + m + v1.x, m + u1,
                                (v0.z + v0.w) + u2, v0.w + (u2 + v1.w));
            }
        }
        BAR();

        // ---- Phase C: y box-sum + cc + weighted accumulate, all 256 threads
        if (s >= 4) {   // uniform: output plane zo = c0-4+s is in range
            float2 S[5];
#pragma unroll
            for (int a = 0; a < 5; ++a) {
                float2 v = *(const float2*)&sx[a][cty][cx0];
#pragma unroll
                for (int k = 1; k < 5; ++k) {
                    const float2 w = *(const float2*)&sx[a][cty + k][cx0];
                    v.x += w.x; v.y += w.y;
                }
                S[a] = v;
            }
            {
                const float cr = S[4].x - S[0].x * S[1].x * inv125;
                const float vi = S[2].x - S[0].x * S[0].x * inv125;
                const float vj = S[3].x - S[1].x * S[1].x * inv125;
                acc += wmCx * (cr * cr) * __builtin_amdgcn_rcpf(vi * vj + 1e-8f);
            }
            {
                const float cr = S[4].y - S[0].y * S[1].y * inv125;
                const float vi = S[2].y - S[0].y * S[0].y * inv125;
                const float vj = S[3].y - S[1].y * S[1].y * inv125;
                acc += wmCy * (cr * cr) * __builtin_amdgcn_rcpf(vi * vj + 1e-8f);
            }
        }

        // ---- rotate pipeline registers (apply masks to prefetched plane)
        {
            const float f0 = (mH && mW0 && mZn) ? 1.f : 0.f;
            const float f1 = (mH && mW1 && mZn) ? 1.f : 0.f;
            cI[0]=pi0.x*f0; cI[1]=pi0.y*f0; cI[2]=pi1.x*f1; cI[3]=pi1.y*f1;
            cJ[0]=pj0.x*f0; cJ[1]=pj0.y*f0; cJ[2]=pj1.x*f1; cJ[3]=pj1.y*f1;
        }
        wmCx = wmN.x; wmCy = wmN.y;
        // next Phase A overwrites zsL: safe — every wave drained its B-reads
        // before the second barrier; Phase C only touches sx, whose next writer
        // (Phase B) is beyond the next first barrier.
    }

    // Block reduction: wave64 shuffle, then cross-wave via LDS
#pragma unroll
    for (int off = 32; off > 0; off >>= 1)
        acc += __shfl_down(acc, off, 64);
    const int wave = tid >> 6;
    const int lane = tid & 63;
    if (lane == 0) red[wave] = acc;
    __syncthreads();
    if (tid == 0) {
        const float t = red[0] + red[1] + red[2] + red[3];
        atomicAdd(out, t * (-1.0f / (float)TOT));
    }
}

extern "C" void kernel_launch(void* const* d_in, const int* in_sizes, int n_in,
                              void* d_out, int out_size, void* d_ws, size_t ws_size,
                              hipStream_t stream)
{
    const float* I  = (const float*)d_in[0];
    const float* J  = (const float*)d_in[1];
    const float* Wm = (const float*)d_in[2];
    float* out = (float*)d_out;

    hipMemsetAsync(out, 0, sizeof(float), stream);

    dim3 grid(W_ / TW, H_ / TH, N_ * NZC);  // (7, 12, 10) = 840 blocks
    dim3 block(256);
    hipLaunchKernelGGL(ncc_kernel, grid, block, 0, stream, I, J, Wm, out);
}